// Round 3
// baseline (105686.243 us; speedup 1.0000x reference)
//
#include <hip/hip_runtime.h>
#include <hip/hip_cooperative_groups.h>

namespace cg = cooperative_groups;

#define HIDDEN   2048
#define VOCAB    7
#define STEPS    1024
#define NBLOCKS  512
#define NTHREADS 256
#define NWAVES   (NTHREADS / 64)

typedef unsigned long long u64;

// Cross-block state in device globals (no dependence on ws sizing/poison).
__device__ float g_h[2][HIDDEN];            // h ping-pong
__device__ float g_c[HIDDEN];               // fallback path only
__device__ float g_part[NBLOCKS * VOCAB];   // per-block logit partials
__device__ int   g_xi;                      // greedy-feedback token index
__device__ int   g_cnt;                     // monotonic arrive counter

__device__ __forceinline__ float sigm(float x) { return 1.0f / (1.0f + expf(-x)); }

#define LOAD_AG(p)     __hip_atomic_load((p), __ATOMIC_RELAXED, __HIP_MEMORY_SCOPE_AGENT)
#define LOADACQ_AG(p)  __hip_atomic_load((p), __ATOMIC_ACQUIRE, __HIP_MEMORY_SCOPE_AGENT)
#define STORE_AG(p, v) __hip_atomic_store((p), (v), __ATOMIC_RELAXED, __HIP_MEMORY_SCOPE_AGENT)
#define STOREREL_AG(p, v) __hip_atomic_store((p), (v), __ATOMIC_RELEASE, __HIP_MEMORY_SCOPE_AGENT)

// Load h[4m..4m+3] as two 8B device-scope atomic loads (bypass stale L1/L2).
__device__ __forceinline__ float4 h_pair(const u64* h8, int m) {
    u64 lo = __hip_atomic_load((u64*)&h8[2 * m],     __ATOMIC_RELAXED, __HIP_MEMORY_SCOPE_AGENT);
    u64 hi = __hip_atomic_load((u64*)&h8[2 * m + 1], __ATOMIC_RELAXED, __HIP_MEMORY_SCOPE_AGENT);
    float4 r;
    r.x = __uint_as_float((unsigned)lo);
    r.y = __uint_as_float((unsigned)(lo >> 32));
    r.z = __uint_as_float((unsigned)hi);
    r.w = __uint_as_float((unsigned)(hi >> 32));
    return r;
}

// ---------------- cooperative single-dispatch kernel ----------------
__global__ __launch_bounds__(NTHREADS, 2)
void coop_kernel(const float* __restrict__ h0,  const float* __restrict__ c0,
                 const float* __restrict__ W_ih, const float* __restrict__ W_hh,
                 const float* __restrict__ b_ih, const float* __restrict__ b_hh,
                 const float* __restrict__ W_out, const float* __restrict__ b_out,
                 float* __restrict__ out)
{
    cg::grid_group grid = cg::this_grid();
    const int tid  = threadIdx.x;
    const int gid  = blockIdx.x * NTHREADS + tid;
    const int lane = tid & 63;
    const int wib  = tid >> 6;
    const int j    = blockIdx.x * NWAVES + wib;   // hidden unit, 0..2047

    __shared__ float s_part[NWAVES][VOCAB];
    __shared__ int   s_last;

    // ---- init cross-block state with device-scope atomics ----
    if (gid < HIDDEN) STORE_AG(&g_h[0][gid], h0[gid]);
    if (gid == 0)     { STORE_AG(&g_xi, VOCAB - 1); STORE_AG(&g_cnt, 0); }

    const float4* Wr0 = (const float4*)(W_hh + (size_t)j * HIDDEN);
    const float4* Wr1 = (const float4*)(W_hh + (size_t)(j + HIDDEN) * HIDDEN);
    const float4* Wr2 = (const float4*)(W_hh + (size_t)(j + 2 * HIDDEN) * HIDDEN);
    const float4* Wr3 = (const float4*)(W_hh + (size_t)(j + 3 * HIDDEN) * HIDDEN);

    float bsum0 = 0.f, bsum1 = 0.f, bsum2 = 0.f, bsum3 = 0.f;
    float cv = 0.f, h_fin = 0.f;
    if (lane == 0) {
        bsum0 = b_ih[j]              + b_hh[j];
        bsum1 = b_ih[j + HIDDEN]     + b_hh[j + HIDDEN];
        bsum2 = b_ih[j + 2 * HIDDEN] + b_hh[j + 2 * HIDDEN];
        bsum3 = b_ih[j + 3 * HIDDEN] + b_hh[j + 3 * HIDDEN];
        cv = c0[j];                               // c lives in a register all 1024 steps
    }
    const float wout = (lane < VOCAB) ? W_out[lane * HIDDEN + j] : 0.0f;

    grid.sync();

    for (int t = 0; t < STEPS; ++t) {
        const u64* h8 = (const u64*)g_h[t & 1];

        int xi = 0;
        if (lane == 0) xi = LOADACQ_AG(&g_xi);

        float4 hreg[8];
        #pragma unroll
        for (int it = 0; it < 8; ++it) hreg[it] = h_pair(h8, it * 64 + lane);

        float a0 = 0.f, a1 = 0.f, a2 = 0.f, a3 = 0.f;
        #pragma unroll
        for (int it = 0; it < 8; ++it) {
            const float4 hv = hreg[it];
            const float4 w0 = Wr0[it * 64 + lane];
            const float4 w1 = Wr1[it * 64 + lane];
            const float4 w2 = Wr2[it * 64 + lane];
            const float4 w3 = Wr3[it * 64 + lane];
            a0 += w0.x * hv.x + w0.y * hv.y + w0.z * hv.z + w0.w * hv.w;
            a1 += w1.x * hv.x + w1.y * hv.y + w1.z * hv.z + w1.w * hv.w;
            a2 += w2.x * hv.x + w2.y * hv.y + w2.z * hv.z + w2.w * hv.w;
            a3 += w3.x * hv.x + w3.y * hv.y + w3.z * hv.z + w3.w * hv.w;
        }
        #pragma unroll
        for (int off = 32; off > 0; off >>= 1) {
            a0 += __shfl_down(a0, off, 64);
            a1 += __shfl_down(a1, off, 64);
            a2 += __shfl_down(a2, off, 64);
            a3 += __shfl_down(a3, off, 64);
        }

        float h2v = 0.0f;
        if (lane == 0) {
            const float gi = a0 + bsum0 + W_ih[j * VOCAB + xi];
            const float gf = a1 + bsum1 + W_ih[(j + HIDDEN) * VOCAB + xi];
            const float gg = a2 + bsum2 + W_ih[(j + 2 * HIDDEN) * VOCAB + xi];
            const float go = a3 + bsum3 + W_ih[(j + 3 * HIDDEN) * VOCAB + xi];
            cv  = sigm(gf) * cv + sigm(gi) * tanhf(gg);
            h2v = sigm(go) * tanhf(cv);
            h_fin = h2v;
            STOREREL_AG(&g_h[(t + 1) & 1][j], h2v);   // device-scope, bypasses L1/L2
        }
        h2v = __shfl(h2v, 0, 64);

        if (lane < VOCAB) s_part[wib][lane] = h2v * wout;
        __syncthreads();   // drains vmcnt too (HIP __syncthreads semantics)
        if (tid < VOCAB) {
            STORE_AG(&g_part[blockIdx.x * VOCAB + tid],
                     s_part[0][tid] + s_part[1][tid] + s_part[2][tid] + s_part[3][tid]);
        }
        __syncthreads();   // all partial stores drained before the arrive RMW
        if (tid == 0) {
            int old = __hip_atomic_fetch_add(&g_cnt, 1, __ATOMIC_ACQ_REL, __HIP_MEMORY_SCOPE_AGENT);
            s_last = (old == (t + 1) * NBLOCKS - 1) ? 1 : 0;   // monotonic, never reset
        }
        __syncthreads();
        if (s_last) {
            if (tid < 64) {
                float lg[VOCAB];
                #pragma unroll
                for (int v = 0; v < VOCAB; ++v) {
                    float s = 0.0f;
                    for (int i = lane; i < NBLOCKS; i += 64)
                        s += LOAD_AG(&g_part[i * VOCAB + v]);
                    #pragma unroll
                    for (int off = 32; off > 0; off >>= 1) s += __shfl_down(s, off, 64);
                    lg[v] = s;
                }
                if (lane == 0) {
                    float l[VOCAB];
                    float mx = -1e30f;
                    #pragma unroll
                    for (int v = 0; v < VOCAB; ++v) { l[v] = lg[v] + b_out[v]; mx = fmaxf(mx, l[v]); }
                    float se = 0.0f;
                    #pragma unroll
                    for (int v = 0; v < VOCAB; ++v) se += expf(l[v] - mx);
                    const float lse = mx + logf(se);
                    int am = 0; float best = l[0];
                    #pragma unroll
                    for (int v = 1; v < VOCAB; ++v) if (l[v] > best) { best = l[v]; am = v; }
                    #pragma unroll
                    for (int v = 0; v < VOCAB; ++v) out[t * VOCAB + v] = l[v] - lse;
                    STOREREL_AG(&g_xi, am);           // greedy feedback, device-scope
                }
            }
        }
        // Own stores at the coherence point before anyone passes the barrier,
        // independent of grid.sync's internal fence scope.
        asm volatile("s_waitcnt vmcnt(0)" ::: "memory");
        grid.sync();
    }

    // final state straight from registers
    if (lane == 0) {
        out[STEPS * VOCAB + j]          = h_fin;
        out[STEPS * VOCAB + HIDDEN + j] = cv;
    }
}

// ---------------- fallback: sequential per-step kernels ----------------
// Relies only on kernel-boundary coherence (same stream). Used only if the
// cooperative launch is rejected.
__global__ __launch_bounds__(NTHREADS)
void fb_init(const float* __restrict__ h0, const float* __restrict__ c0) {
    int gid = blockIdx.x * NTHREADS + threadIdx.x;
    if (gid < HIDDEN) { g_h[0][gid] = h0[gid]; g_c[gid] = c0[gid]; }
    if (gid == 0) g_xi = VOCAB - 1;
}

__global__ __launch_bounds__(NTHREADS, 2)
void fb_step(const float* __restrict__ W_ih, const float* __restrict__ W_hh,
             const float* __restrict__ b_ih, const float* __restrict__ b_hh,
             const float* __restrict__ W_out, int t)
{
    const int tid  = threadIdx.x;
    const int lane = tid & 63;
    const int wib  = tid >> 6;
    const int j    = blockIdx.x * NWAVES + wib;

    __shared__ float s_part[NWAVES][VOCAB];

    const float4* h4 = (const float4*)g_h[t & 1];
    const float4* Wr0 = (const float4*)(W_hh + (size_t)j * HIDDEN);
    const float4* Wr1 = (const float4*)(W_hh + (size_t)(j + HIDDEN) * HIDDEN);
    const float4* Wr2 = (const float4*)(W_hh + (size_t)(j + 2 * HIDDEN) * HIDDEN);
    const float4* Wr3 = (const float4*)(W_hh + (size_t)(j + 3 * HIDDEN) * HIDDEN);

    float a0 = 0.f, a1 = 0.f, a2 = 0.f, a3 = 0.f;
    #pragma unroll
    for (int it = 0; it < 8; ++it) {
        const float4 hv = h4[it * 64 + lane];
        const float4 w0 = Wr0[it * 64 + lane];
        const float4 w1 = Wr1[it * 64 + lane];
        const float4 w2 = Wr2[it * 64 + lane];
        const float4 w3 = Wr3[it * 64 + lane];
        a0 += w0.x * hv.x + w0.y * hv.y + w0.z * hv.z + w0.w * hv.w;
        a1 += w1.x * hv.x + w1.y * hv.y + w1.z * hv.z + w1.w * hv.w;
        a2 += w2.x * hv.x + w2.y * hv.y + w2.z * hv.z + w2.w * hv.w;
        a3 += w3.x * hv.x + w3.y * hv.y + w3.z * hv.z + w3.w * hv.w;
    }
    #pragma unroll
    for (int off = 32; off > 0; off >>= 1) {
        a0 += __shfl_down(a0, off, 64);
        a1 += __shfl_down(a1, off, 64);
        a2 += __shfl_down(a2, off, 64);
        a3 += __shfl_down(a3, off, 64);
    }

    float h2v = 0.0f;
    if (lane == 0) {
        const int xi = g_xi;
        const float gi = a0 + b_ih[j] + b_hh[j] + W_ih[j * VOCAB + xi];
        const float gf = a1 + b_ih[j + HIDDEN] + b_hh[j + HIDDEN] + W_ih[(j + HIDDEN) * VOCAB + xi];
        const float gg = a2 + b_ih[j + 2 * HIDDEN] + b_hh[j + 2 * HIDDEN] + W_ih[(j + 2 * HIDDEN) * VOCAB + xi];
        const float go = a3 + b_ih[j + 3 * HIDDEN] + b_hh[j + 3 * HIDDEN] + W_ih[(j + 3 * HIDDEN) * VOCAB + xi];
        const float cv = sigm(gf) * g_c[j] + sigm(gi) * tanhf(gg);
        h2v = sigm(go) * tanhf(cv);
        g_c[j] = cv;
        g_h[(t + 1) & 1][j] = h2v;
    }
    h2v = __shfl(h2v, 0, 64);

    const float wout = (lane < VOCAB) ? W_out[lane * HIDDEN + j] : 0.0f;
    if (lane < VOCAB) s_part[wib][lane] = h2v * wout;
    __syncthreads();
    if (tid < VOCAB)
        g_part[blockIdx.x * VOCAB + tid] =
            s_part[0][tid] + s_part[1][tid] + s_part[2][tid] + s_part[3][tid];
}

__global__ void fb_logits(const float* __restrict__ b_out, float* __restrict__ out, int t) {
    const int lane = threadIdx.x;   // 64 threads
    float lg[VOCAB];
    #pragma unroll
    for (int v = 0; v < VOCAB; ++v) {
        float s = 0.0f;
        for (int i = lane; i < NBLOCKS; i += 64) s += g_part[i * VOCAB + v];
        #pragma unroll
        for (int off = 32; off > 0; off >>= 1) s += __shfl_down(s, off, 64);
        lg[v] = s;
    }
    if (lane == 0) {
        float l[VOCAB];
        float mx = -1e30f;
        #pragma unroll
        for (int v = 0; v < VOCAB; ++v) { l[v] = lg[v] + b_out[v]; mx = fmaxf(mx, l[v]); }
        float se = 0.0f;
        #pragma unroll
        for (int v = 0; v < VOCAB; ++v) se += expf(l[v] - mx);
        const float lse = mx + logf(se);
        int am = 0; float best = l[0];
        #pragma unroll
        for (int v = 1; v < VOCAB; ++v) if (l[v] > best) { best = l[v]; am = v; }
        #pragma unroll
        for (int v = 0; v < VOCAB; ++v) out[t * VOCAB + v] = l[v] - lse;
        g_xi = am;
    }
}

__global__ __launch_bounds__(NTHREADS)
void fb_fin(float* __restrict__ out) {
    int gid = blockIdx.x * NTHREADS + threadIdx.x;
    if (gid < HIDDEN) {
        out[STEPS * VOCAB + gid]          = g_h[0][gid];
        out[STEPS * VOCAB + HIDDEN + gid] = g_c[gid];
    }
}

extern "C" void kernel_launch(void* const* d_in, const int* in_sizes, int n_in,
                              void* d_out, int out_size, void* d_ws, size_t ws_size,
                              hipStream_t stream)
{
    const float* h0    = (const float*)d_in[0];
    const float* c0    = (const float*)d_in[1];
    const float* W_ih  = (const float*)d_in[2];
    const float* W_hh  = (const float*)d_in[3];
    const float* b_ih  = (const float*)d_in[4];
    const float* b_hh  = (const float*)d_in[5];
    const float* W_out = (const float*)d_in[6];
    const float* b_out = (const float*)d_in[7];
    float* out = (float*)d_out;

    void* args[] = { &h0, &c0, &W_ih, &W_hh, &b_ih, &b_hh, &W_out, &b_out, &out };
    hipError_t e = hipLaunchCooperativeKernel((void*)coop_kernel,
                                              dim3(NBLOCKS), dim3(NTHREADS), args, 0, stream);
    if (e != hipSuccess) {
        // Sequential fallback: kernel-boundary coherence only.
        fb_init<<<HIDDEN / NTHREADS, NTHREADS, 0, stream>>>(h0, c0);
        for (int t = 0; t < STEPS; ++t) {
            fb_step<<<NBLOCKS, NTHREADS, 0, stream>>>(W_ih, W_hh, b_ih, b_hh, W_out, t);
            fb_logits<<<1, 64, 0, stream>>>(b_out, out, t);
        }
        fb_fin<<<HIDDEN / NTHREADS, NTHREADS, 0, stream>>>(out);
    }
}

// Round 4
// 85604.852 us; speedup vs baseline: 1.2346x; 1.2346x over previous
//
#include <hip/hip_runtime.h>
#include <hip/hip_cooperative_groups.h>

namespace cg = cooperative_groups;

#define HIDDEN   2048
#define VOCAB    7
#define STEPS    1024
#define NBLOCKS  512
#define NTHREADS 256
#define NWAVES   (NTHREADS / 64)

typedef unsigned long long u64;

// Cross-block state in device globals.
__device__ float g_h[3][HIDDEN];            // h triple-buffer (skew <= 1 step)
__device__ float g_c[HIDDEN];               // fallback path only
__device__ float g_part[NBLOCKS * VOCAB];   // per-block logit partials
__device__ u64   g_genxi;                   // (generation<<32) | argmax  -- THE barrier word
__device__ int   g_cnt;                     // monotonic arrive counter
__device__ int   g_xi;                      // fallback path only

__device__ __forceinline__ float sigm(float x) { return 1.0f / (1.0f + expf(-x)); }

#define LOAD_AG(p)        __hip_atomic_load((p), __ATOMIC_RELAXED, __HIP_MEMORY_SCOPE_AGENT)
#define LOADACQ_AG(p)     __hip_atomic_load((p), __ATOMIC_ACQUIRE, __HIP_MEMORY_SCOPE_AGENT)
#define STORE_AG(p, v)    __hip_atomic_store((p), (v), __ATOMIC_RELAXED, __HIP_MEMORY_SCOPE_AGENT)
#define STOREREL_AG(p, v) __hip_atomic_store((p), (v), __ATOMIC_RELEASE, __HIP_MEMORY_SCOPE_AGENT)

// Load h[4m..4m+3] as two 8B agent-scope loads (bypass stale L1/L2).
__device__ __forceinline__ float4 h_pair(const u64* h8, int m) {
    u64 lo = __hip_atomic_load((u64*)&h8[2 * m],     __ATOMIC_RELAXED, __HIP_MEMORY_SCOPE_AGENT);
    u64 hi = __hip_atomic_load((u64*)&h8[2 * m + 1], __ATOMIC_RELAXED, __HIP_MEMORY_SCOPE_AGENT);
    float4 r;
    r.x = __uint_as_float((unsigned)lo);
    r.y = __uint_as_float((unsigned)(lo >> 32));
    r.z = __uint_as_float((unsigned)hi);
    r.w = __uint_as_float((unsigned)(hi >> 32));
    return r;
}

// Register-array select with compile-time indices only (no scratch).
__device__ __forceinline__ float sel7(const float w[VOCAB], int xi) {
    float r = w[0];
    #pragma unroll
    for (int v = 1; v < VOCAB; ++v) r = (xi == v) ? w[v] : r;
    return r;
}

// ---------------- cooperative single-dispatch kernel ----------------
__global__ __launch_bounds__(NTHREADS, 2)
void coop_kernel(const float* __restrict__ h0,  const float* __restrict__ c0,
                 const float* __restrict__ W_ih, const float* __restrict__ W_hh,
                 const float* __restrict__ b_ih, const float* __restrict__ b_hh,
                 const float* __restrict__ W_out, const float* __restrict__ b_out,
                 float* __restrict__ out)
{
    cg::grid_group grid = cg::this_grid();
    const int tid  = threadIdx.x;
    const int gid  = blockIdx.x * NTHREADS + tid;
    const int lane = tid & 63;
    const int wib  = tid >> 6;
    const int j    = blockIdx.x * NWAVES + wib;   // hidden unit, 0..2047

    __shared__ float s_part[NWAVES][VOCAB];
    __shared__ int   s_last;
    __shared__ u64   s_gx;

    // ---- per-launch init (replay-safe) ----
    if (gid < HIDDEN) STORE_AG(&g_h[0][gid], h0[gid]);
    if (gid == 0)     { STORE_AG(&g_genxi, (u64)(VOCAB - 1)); STORE_AG(&g_cnt, 0); }

    const float4* Wr0 = (const float4*)(W_hh + (size_t)j * HIDDEN);
    const float4* Wr1 = (const float4*)(W_hh + (size_t)(j + HIDDEN) * HIDDEN);
    const float4* Wr2 = (const float4*)(W_hh + (size_t)(j + 2 * HIDDEN) * HIDDEN);
    const float4* Wr3 = (const float4*)(W_hh + (size_t)(j + 3 * HIDDEN) * HIDDEN);

    float bsum0 = 0.f, bsum1 = 0.f, bsum2 = 0.f, bsum3 = 0.f;
    float cv = 0.f, h_fin = 0.f;
    float wih0[VOCAB], wih1[VOCAB], wih2[VOCAB], wih3[VOCAB];
    if (lane == 0) {
        bsum0 = b_ih[j]              + b_hh[j];
        bsum1 = b_ih[j + HIDDEN]     + b_hh[j + HIDDEN];
        bsum2 = b_ih[j + 2 * HIDDEN] + b_hh[j + 2 * HIDDEN];
        bsum3 = b_ih[j + 3 * HIDDEN] + b_hh[j + 3 * HIDDEN];
        cv = c0[j];                               // c lives in a register all 1024 steps
        #pragma unroll
        for (int v = 0; v < VOCAB; ++v) {
            wih0[v] = W_ih[(size_t)j * VOCAB + v];
            wih1[v] = W_ih[(size_t)(j + HIDDEN) * VOCAB + v];
            wih2[v] = W_ih[(size_t)(j + 2 * HIDDEN) * VOCAB + v];
            wih3[v] = W_ih[(size_t)(j + 3 * HIDDEN) * VOCAB + v];
        }
    }
    const float wout = (lane < VOCAB) ? W_out[lane * HIDDEN + j] : 0.0f;
    float bov[VOCAB];
    #pragma unroll
    for (int v = 0; v < VOCAB; ++v) bov[v] = b_out[v];

    grid.sync();   // ONE cooperative barrier, init only — not in the loop

    int xi = VOCAB - 1;          // SOS
    int rb = 0, wbuf = 1;        // h read/write buffer indices (mod 3)

    for (int t = 0; t < STEPS; ++t) {
        const u64* h8 = (const u64*)g_h[rb];

        float4 hreg[8];
        #pragma unroll
        for (int it = 0; it < 8; ++it) hreg[it] = h_pair(h8, it * 64 + lane);

        float a0 = 0.f, a1 = 0.f, a2 = 0.f, a3 = 0.f;
        #pragma unroll
        for (int it = 0; it < 8; ++it) {
            const float4 hv = hreg[it];
            const float4 w0 = Wr0[it * 64 + lane];
            const float4 w1 = Wr1[it * 64 + lane];
            const float4 w2 = Wr2[it * 64 + lane];
            const float4 w3 = Wr3[it * 64 + lane];
            a0 += w0.x * hv.x + w0.y * hv.y + w0.z * hv.z + w0.w * hv.w;
            a1 += w1.x * hv.x + w1.y * hv.y + w1.z * hv.z + w1.w * hv.w;
            a2 += w2.x * hv.x + w2.y * hv.y + w2.z * hv.z + w2.w * hv.w;
            a3 += w3.x * hv.x + w3.y * hv.y + w3.z * hv.z + w3.w * hv.w;
        }
        #pragma unroll
        for (int off = 32; off > 0; off >>= 1) {
            a0 += __shfl_down(a0, off, 64);
            a1 += __shfl_down(a1, off, 64);
            a2 += __shfl_down(a2, off, 64);
            a3 += __shfl_down(a3, off, 64);
        }

        float h2v = 0.0f;
        if (lane == 0) {
            const float gi = a0 + bsum0 + sel7(wih0, xi);
            const float gf = a1 + bsum1 + sel7(wih1, xi);
            const float gg = a2 + bsum2 + sel7(wih2, xi);
            const float go = a3 + bsum3 + sel7(wih3, xi);
            cv  = sigm(gf) * cv + sigm(gi) * tanhf(gg);
            h2v = sigm(go) * tanhf(cv);
            h_fin = h2v;
            STOREREL_AG(&g_h[wbuf][j], h2v);
        }
        h2v = __shfl(h2v, 0, 64);

        if (lane < VOCAB) s_part[wib][lane] = h2v * wout;
        __syncthreads();
        if (tid < VOCAB) {
            STORE_AG(&g_part[blockIdx.x * VOCAB + tid],
                     s_part[0][tid] + s_part[1][tid] + s_part[2][tid] + s_part[3][tid]);
        }
        // fetch_add is ACQ_REL: compiler drains this wave's prior stores
        // (lanes 0..6 partial stores + lane0 h store) before the RMW.
        if (tid == 0) {
            int old = __hip_atomic_fetch_add(&g_cnt, 1, __ATOMIC_ACQ_REL, __HIP_MEMORY_SCOPE_AGENT);
            s_last = (old == (t + 1) * NBLOCKS - 1) ? 1 : 0;   // monotonic
        }
        __syncthreads();
        if (s_last) {
            // tail: wave 0 reduces 512 partials, publishes (gen, argmax)
            if (tid < 64) {
                float lg[VOCAB];
                #pragma unroll
                for (int v = 0; v < VOCAB; ++v) {
                    float s = 0.0f;
                    #pragma unroll
                    for (int k = 0; k < NBLOCKS / 64; ++k)
                        s += LOAD_AG(&g_part[(k * 64 + lane) * VOCAB + v]);
                    #pragma unroll
                    for (int off = 32; off > 0; off >>= 1) s += __shfl_down(s, off, 64);
                    lg[v] = s;
                }
                if (lane == 0) {
                    float l[VOCAB];
                    float mx = -1e30f;
                    #pragma unroll
                    for (int v = 0; v < VOCAB; ++v) { l[v] = lg[v] + bov[v]; mx = fmaxf(mx, l[v]); }
                    float se = 0.0f;
                    #pragma unroll
                    for (int v = 0; v < VOCAB; ++v) se += expf(l[v] - mx);
                    const float lse = mx + logf(se);
                    int am = 0; float best = l[0];
                    #pragma unroll
                    for (int v = 1; v < VOCAB; ++v) if (l[v] > best) { best = l[v]; am = v; }
                    #pragma unroll
                    for (int v = 0; v < VOCAB; ++v) out[t * VOCAB + v] = l[v] - lse;
                    // THE barrier release: publish generation + greedy token.
                    STOREREL_AG(&g_genxi, ((u64)(unsigned)(t + 1) << 32) | (u64)(unsigned)am);
                }
            }
        }
        // Fused barrier: spin on the generation word (tid 0 only), broadcast via LDS.
        if (t + 1 < STEPS) {
            if (tid == 0) {
                u64 cur = LOADACQ_AG(&g_genxi);
                while ((unsigned)(cur >> 32) != (unsigned)(t + 1)) {
                    __builtin_amdgcn_s_sleep(1);
                    cur = LOADACQ_AG(&g_genxi);
                }
                s_gx = cur;
            }
            __syncthreads();
            xi = (int)(unsigned)s_gx;
        }
        rb = wbuf;
        wbuf = (wbuf + 1 == 3) ? 0 : wbuf + 1;
    }

    // final state straight from registers
    if (lane == 0) {
        out[STEPS * VOCAB + j]          = h_fin;
        out[STEPS * VOCAB + HIDDEN + j] = cv;
    }
}

// ---------------- fallback: sequential per-step kernels ----------------
__global__ __launch_bounds__(NTHREADS)
void fb_init(const float* __restrict__ h0, const float* __restrict__ c0) {
    int gid = blockIdx.x * NTHREADS + threadIdx.x;
    if (gid < HIDDEN) { g_h[0][gid] = h0[gid]; g_c[gid] = c0[gid]; }
    if (gid == 0) g_xi = VOCAB - 1;
}

__global__ __launch_bounds__(NTHREADS, 2)
void fb_step(const float* __restrict__ W_ih, const float* __restrict__ W_hh,
             const float* __restrict__ b_ih, const float* __restrict__ b_hh,
             const float* __restrict__ W_out, int t)
{
    const int tid  = threadIdx.x;
    const int lane = tid & 63;
    const int wib  = tid >> 6;
    const int j    = blockIdx.x * NWAVES + wib;

    __shared__ float s_part[NWAVES][VOCAB];

    const float4* h4 = (const float4*)g_h[t & 1];
    const float4* Wr0 = (const float4*)(W_hh + (size_t)j * HIDDEN);
    const float4* Wr1 = (const float4*)(W_hh + (size_t)(j + HIDDEN) * HIDDEN);
    const float4* Wr2 = (const float4*)(W_hh + (size_t)(j + 2 * HIDDEN) * HIDDEN);
    const float4* Wr3 = (const float4*)(W_hh + (size_t)(j + 3 * HIDDEN) * HIDDEN);

    float a0 = 0.f, a1 = 0.f, a2 = 0.f, a3 = 0.f;
    #pragma unroll
    for (int it = 0; it < 8; ++it) {
        const float4 hv = h4[it * 64 + lane];
        const float4 w0 = Wr0[it * 64 + lane];
        const float4 w1 = Wr1[it * 64 + lane];
        const float4 w2 = Wr2[it * 64 + lane];
        const float4 w3 = Wr3[it * 64 + lane];
        a0 += w0.x * hv.x + w0.y * hv.y + w0.z * hv.z + w0.w * hv.w;
        a1 += w1.x * hv.x + w1.y * hv.y + w1.z * hv.z + w1.w * hv.w;
        a2 += w2.x * hv.x + w2.y * hv.y + w2.z * hv.z + w2.w * hv.w;
        a3 += w3.x * hv.x + w3.y * hv.y + w3.z * hv.z + w3.w * hv.w;
    }
    #pragma unroll
    for (int off = 32; off > 0; off >>= 1) {
        a0 += __shfl_down(a0, off, 64);
        a1 += __shfl_down(a1, off, 64);
        a2 += __shfl_down(a2, off, 64);
        a3 += __shfl_down(a3, off, 64);
    }

    float h2v = 0.0f;
    if (lane == 0) {
        const int xi = g_xi;
        const float gi = a0 + b_ih[j] + b_hh[j] + W_ih[j * VOCAB + xi];
        const float gf = a1 + b_ih[j + HIDDEN] + b_hh[j + HIDDEN] + W_ih[(j + HIDDEN) * VOCAB + xi];
        const float gg = a2 + b_ih[j + 2 * HIDDEN] + b_hh[j + 2 * HIDDEN] + W_ih[(j + 2 * HIDDEN) * VOCAB + xi];
        const float go = a3 + b_ih[j + 3 * HIDDEN] + b_hh[j + 3 * HIDDEN] + W_ih[(j + 3 * HIDDEN) * VOCAB + xi];
        const float cv = sigm(gf) * g_c[j] + sigm(gi) * tanhf(gg);
        h2v = sigm(go) * tanhf(cv);
        g_c[j] = cv;
        g_h[(t + 1) & 1][j] = h2v;
    }
    h2v = __shfl(h2v, 0, 64);

    const float wout = (lane < VOCAB) ? W_out[lane * HIDDEN + j] : 0.0f;
    if (lane < VOCAB) s_part[wib][lane] = h2v * wout;
    __syncthreads();
    if (tid < VOCAB)
        g_part[blockIdx.x * VOCAB + tid] =
            s_part[0][tid] + s_part[1][tid] + s_part[2][tid] + s_part[3][tid];
}

__global__ void fb_logits(const float* __restrict__ b_out, float* __restrict__ out, int t) {
    const int lane = threadIdx.x;   // 64 threads
    float lg[VOCAB];
    #pragma unroll
    for (int v = 0; v < VOCAB; ++v) {
        float s = 0.0f;
        for (int i = lane; i < NBLOCKS; i += 64) s += g_part[i * VOCAB + v];
        #pragma unroll
        for (int off = 32; off > 0; off >>= 1) s += __shfl_down(s, off, 64);
        lg[v] = s;
    }
    if (lane == 0) {
        float l[VOCAB];
        float mx = -1e30f;
        #pragma unroll
        for (int v = 0; v < VOCAB; ++v) { l[v] = lg[v] + b_out[v]; mx = fmaxf(mx, l[v]); }
        float se = 0.0f;
        #pragma unroll
        for (int v = 0; v < VOCAB; ++v) se += expf(l[v] - mx);
        const float lse = mx + logf(se);
        int am = 0; float best = l[0];
        #pragma unroll
        for (int v = 1; v < VOCAB; ++v) if (l[v] > best) { best = l[v]; am = v; }
        #pragma unroll
        for (int v = 0; v < VOCAB; ++v) out[t * VOCAB + v] = l[v] - lse;
        g_xi = am;
    }
}

__global__ __launch_bounds__(NTHREADS)
void fb_fin(float* __restrict__ out) {
    int gid = blockIdx.x * NTHREADS + threadIdx.x;
    if (gid < HIDDEN) {
        out[STEPS * VOCAB + gid]          = g_h[0][gid];
        out[STEPS * VOCAB + HIDDEN + gid] = g_c[gid];
    }
}

extern "C" void kernel_launch(void* const* d_in, const int* in_sizes, int n_in,
                              void* d_out, int out_size, void* d_ws, size_t ws_size,
                              hipStream_t stream)
{
    const float* h0    = (const float*)d_in[0];
    const float* c0    = (const float*)d_in[1];
    const float* W_ih  = (const float*)d_in[2];
    const float* W_hh  = (const float*)d_in[3];
    const float* b_ih  = (const float*)d_in[4];
    const float* b_hh  = (const float*)d_in[5];
    const float* W_out = (const float*)d_in[6];
    const float* b_out = (const float*)d_in[7];
    float* out = (float*)d_out;

    void* args[] = { &h0, &c0, &W_ih, &W_hh, &b_ih, &b_hh, &W_out, &b_out, &out };
    hipError_t e = hipLaunchCooperativeKernel((void*)coop_kernel,
                                              dim3(NBLOCKS), dim3(NTHREADS), args, 0, stream);
    if (e != hipSuccess) {
        fb_init<<<HIDDEN / NTHREADS, NTHREADS, 0, stream>>>(h0, c0);
        for (int t = 0; t < STEPS; ++t) {
            fb_step<<<NBLOCKS, NTHREADS, 0, stream>>>(W_ih, W_hh, b_ih, b_hh, W_out, t);
            fb_logits<<<1, 64, 0, stream>>>(b_out, out, t);
        }
        fb_fin<<<HIDDEN / NTHREADS, NTHREADS, 0, stream>>>(out);
    }
}